// Round 10
// baseline (214.094 us; speedup 1.0000x reference)
//
#include <hip/hip_runtime.h>

// Problem constants
constexpr int Bc = 2, Sc = 2048, Dc = 256, Hc = 8, DKc = 32;
constexpr int BH = Bc * Hc;

typedef _Float16 f16x8 __attribute__((ext_vector_type(8)));
typedef _Float16 f16x4 __attribute__((ext_vector_type(4)));
typedef float    f32x4 __attribute__((ext_vector_type(4)));

// ---------------------------------------------------------------------------
// K1: fused prep.  blocks [0,1536): proj (z=bx/512: 0=Q,1=K^T,2=V^T)
//                  blocks [1536,2560): maskpack (1024 blocks — full coverage)
// ---------------------------------------------------------------------------
__global__ __launch_bounds__(256) void prep_kernel(
    const float* __restrict__ query, const float* __restrict__ key_,
    const float* __restrict__ value, const float* __restrict__ Wq,
    const float* __restrict__ Wk, const float* __restrict__ Wv,
    const unsigned int* __restrict__ mask,
    _Float16* __restrict__ Qb, _Float16* __restrict__ Kt,
    _Float16* __restrict__ Vt, unsigned int* __restrict__ mbits)
{
    __shared__ float xs[8][Dc];
    const int bx = blockIdx.x;
    const int t = threadIdx.x;
    if (bx < 1536) {
        // ---- projection ----
        constexpr int ROWS = 8;
        const int z = bx >> 9;
        const int lb = bx & 511;
        const float* X = (z == 0) ? query : (z == 1) ? key_ : value;
        const float* W = (z == 0) ? Wq : (z == 1) ? Wk : Wv;
        _Float16* out = (z == 0) ? Qb : (z == 1) ? Kt : Vt;
        const int vtrans = (z != 0);
        const float scale = (z == 0) ? 0.17677669529663689f : 1.0f;
        const int r0 = lb * ROWS;
        #pragma unroll
        for (int i = 0; i < ROWS; ++i)
            xs[i][t] = X[(long)(r0 + i) * Dc + t];
        __syncthreads();
        float acc[ROWS];
        #pragma unroll
        for (int i = 0; i < ROWS; ++i) acc[i] = 0.f;
        for (int d = 0; d < Dc; ++d) {
            float w = W[d * Dc + t];
            #pragma unroll
            for (int i = 0; i < ROWS; ++i) acc[i] = fmaf(xs[i][d], w, acc[i]);
        }
        const int h = t >> 5, dk = t & 31;
        #pragma unroll
        for (int i = 0; i < ROWS; ++i) {
            int row = r0 + i;
            int b = row >> 11, s = row & 2047;
            long idx = vtrans ? (((long)(b * Hc + h) * DKc + dk) * Sc + s)
                              : (((long)(b * Hc + h) * Sc + s) * DKc + dk);
            out[idx] = (_Float16)(acc[i] * scale);
        }
    } else {
        // ---- maskpack: 1024 blocks cover all 262144 output uints ----
        const int idx = (bx - 1536) * 256 + t;
        const uint4 a = ((const uint4*)mask)[idx * 2];
        const uint4 b = ((const uint4*)mask)[idx * 2 + 1];
        unsigned int wsv[8] = {a.x, a.y, a.z, a.w, b.x, b.y, b.z, b.w};
        unsigned int r = 0;
        #pragma unroll
        for (int j = 0; j < 8; ++j) {
            unsigned int nib = (wsv[j] | (wsv[j] >> 7) | (wsv[j] >> 14) | (wsv[j] >> 21)) & 0xFu;
            r |= nib << (4 * j);
        }
        mbits[idx] = r;
    }
}

// ---------------------------------------------------------------------------
// K2: KR GEMM with FUSED rel transpose, k-split x4.
// KRp[ks][b][n][hd] = sum_{k in quarter ks} rel[b][k][n] * Kt[b][hd][k]
// Per k-step: stage rel f32 64x64 -> LDS; A-frags read transposed with
// on-the-fly f16 convert (2-way bank alias = free).  Grid (4,32,8)=1024.
// ---------------------------------------------------------------------------
__global__ __launch_bounds__(256) void kr_kernel(
    const float* __restrict__ rel, const _Float16* __restrict__ Kt,
    float* __restrict__ KRp)
{
    __shared__ float tile[64][65];     // rel [k][n] staging (local k)
    __shared__ _Float16 Bs[64][72];    // Kt  [hd][k]
    const int z = blockIdx.z;
    const int b = z >> 2, ks = z & 3;
    const int m0 = blockIdx.y * 64;      // n tile
    const int n0 = blockIdx.x * 64;      // hd tile
    const float* Ap = rel + (long)b * Sc * Sc;
    const _Float16* Bp = Kt + (long)b * Hc * DKc * Sc;
    const int t = threadIdx.x;
    const int lane = t & 63, wave = t >> 6;
    const int wr = wave >> 1, wc = wave & 1;
    const int c = lane & 15, g = lane >> 4;
    const int rr = t >> 4;               // 0..15
    const int c4 = (t & 15) * 4;
    const int lrow = t >> 2;             // 0..63
    const int lcol = (t & 3) * 16;
    f32x4 acc[2][2] = {};
    for (int k0 = ks * 512; k0 < ks * 512 + 512; k0 += 64) {
        #pragma unroll
        for (int i = 0; i < 4; ++i)
            *(f32x4*)&tile[i * 16 + rr][c4] =
                *(const f32x4*)&Ap[(long)(k0 + i * 16 + rr) * Sc + m0 + c4];
        *(f16x8*)&Bs[lrow][lcol]     = *(const f16x8*)&Bp[(long)(n0 + lrow) * Sc + k0 + lcol];
        *(f16x8*)&Bs[lrow][lcol + 8] = *(const f16x8*)&Bp[(long)(n0 + lrow) * Sc + k0 + lcol + 8];
        __syncthreads();
        #pragma unroll
        for (int kk = 0; kk < 2; ++kk) {
            const int kb = kk * 32 + g * 8;
            f16x8 af[2], bf[2];
            #pragma unroll
            for (int m = 0; m < 2; ++m) {
                const int nrow = wr * 32 + m * 16 + c;
                #pragma unroll
                for (int j = 0; j < 8; ++j)
                    af[m][j] = (_Float16)tile[kb + j][nrow];
            }
            #pragma unroll
            for (int n = 0; n < 2; ++n)
                bf[n] = *(const f16x8*)&Bs[wc * 32 + n * 16 + c][kb];
            #pragma unroll
            for (int m = 0; m < 2; ++m)
                #pragma unroll
                for (int n = 0; n < 2; ++n)
                    acc[m][n] = __builtin_amdgcn_mfma_f32_16x16x32_f16(
                        af[m], bf[n], acc[m][n], 0, 0, 0);
        }
        __syncthreads();
    }
    float* outp = KRp + ((long)ks * Bc + b) * Sc * 256;
    #pragma unroll
    for (int m = 0; m < 2; ++m)
        #pragma unroll
        for (int n = 0; n < 2; ++n)
            #pragma unroll
            for (int i = 0; i < 4; ++i) {
                int row = m0 + wr * 32 + m * 16 + g * 4 + i;
                int col = n0 + wc * 32 + n * 16 + c;
                outp[(long)row * 256 + col] = acc[m][n][i];
            }
}

// ---------------------------------------------------------------------------
// K2b: KRT = f16(sum of 4 KRp partials)
// ---------------------------------------------------------------------------
__global__ __launch_bounds__(256) void krc_kernel(
    const float* __restrict__ KRp, _Float16* __restrict__ KRT)
{
    const long idx = ((long)blockIdx.x * 256 + threadIdx.x) * 4;
    const long P = (long)Bc * Sc * 256;
    f32x4 s = {};
    #pragma unroll
    for (int p = 0; p < 4; ++p) {
        f32x4 v = *(const f32x4*)&KRp[p * P + idx];
        #pragma unroll
        for (int i = 0; i < 4; ++i) s[i] += v[i];
    }
    f16x4 o;
    #pragma unroll
    for (int i = 0; i < 4; ++i) o[i] = (_Float16)s[i];
    *(f16x4*)&KRT[idx] = o;
}

// ---------------------------------------------------------------------------
// K3a: esum + PV pass, n-split x4.  grid (32 q-tiles, BH, 4 ns) = 2048.
// Writes partial esum_p[ns][bh][q], UNNORMALIZED accp[ns][bh][q][32].
// ---------------------------------------------------------------------------
__global__ __launch_bounds__(256) void attn_pv_kernel(
    const _Float16* __restrict__ Qb,   // [BH][S][32], pre-scaled
    const _Float16* __restrict__ KRT,  // [B][S][256]
    const _Float16* __restrict__ Vt,   // [BH][32][S]
    const unsigned int* __restrict__ mbits, // [B][S][S/32]
    float* __restrict__ esum_p,        // [4][BH][S]
    float* __restrict__ accp)          // [4][BH][S][32]
{
    constexpr int NT = 128, LDP = 136;
    __shared__ _Float16 p_lds[64][LDP];
    const int bh = blockIdx.y;
    const int ns = blockIdx.z;
    const int b = bh >> 3, h = bh & 7;
    const int q0 = blockIdx.x * 64;
    const int t = threadIdx.x, lane = t & 63, w = t >> 6;
    const int c = lane & 15, g = lane >> 4;
    const int q = q0 + w * 16 + c;
    const f16x8 qf = *(const f16x8*)&Qb[((long)bh * Sc + q) * DKc + g * 8];
    const _Float16* krt = KRT + (long)b * Sc * 256 + h * 32;
    const unsigned int* mbitrow = mbits + ((long)b * Sc + q) * (Sc / 32);
    const f32x4 zero = {};
    f32x4 acc[2] = {};
    float esum = 0.f;

    for (int nt = ns * 4; nt < ns * 4 + 4; ++nt) {
        const int n0 = nt * NT;
        f32x4 s[8];
        #pragma unroll
        for (int nf = 0; nf < 8; ++nf) {
            f16x8 kf = *(const f16x8*)&krt[(long)(n0 + nf * 16 + c) * 256 + g * 8];
            s[nf] = __builtin_amdgcn_mfma_f32_16x16x32_f16(kf, qf, zero, 0, 0, 0);
        }
        const uint4 mq = *(const uint4*)&mbitrow[nt * 4];
        const unsigned int mwv[4] = {mq.x, mq.y, mq.z, mq.w};
        #pragma unroll
        for (int nf = 0; nf < 8; ++nf) {
            const unsigned int bits = mwv[nf >> 1] >> ((nf & 1) * 16 + g * 4);
            f16x4 pv;
            #pragma unroll
            for (int i = 0; i < 4; ++i) {
                float p = ((bits >> i) & 1u) ? 0.f : __expf(s[nf][i]);
                esum += p;
                pv[i] = (_Float16)p;
            }
            *(f16x4*)&p_lds[w * 16 + c][nf * 16 + g * 4] = pv;
        }
        #pragma unroll
        for (int ks = 0; ks < 4; ++ks) {
            f16x8 af = *(const f16x8*)&p_lds[w * 16 + c][ks * 32 + g * 8];
            #pragma unroll
            for (int nb = 0; nb < 2; ++nb) {
                f16x8 vf = *(const f16x8*)&Vt[((long)bh * DKc + nb * 16 + c) * Sc + n0 + ks * 32 + g * 8];
                acc[nb] = __builtin_amdgcn_mfma_f32_16x16x32_f16(af, vf, acc[nb], 0, 0, 0);
            }
        }
    }
    esum += __shfl_xor(esum, 16);
    esum += __shfl_xor(esum, 32);
    if (lane < 16)
        esum_p[((long)ns * BH + bh) * Sc + q0 + w * 16 + lane] = esum;
    #pragma unroll
    for (int nb = 0; nb < 2; ++nb)
        #pragma unroll
        for (int i = 0; i < 4; ++i) {
            const long qrow = q0 + w * 16 + g * 4 + i;
            accp[(((long)ns * BH + bh) * Sc + qrow) * 32 + nb * 16 + c] = acc[nb][i];
        }
}

// ---------------------------------------------------------------------------
// K4: finish.  z<16: attn store tile (nt=x, q-tile=y, bh=z).
//              z==16: LayerNorm output blocks (flat = x*32+y, 8 rows each).
// ---------------------------------------------------------------------------
__global__ __launch_bounds__(256) void finish_kernel(
    const _Float16* __restrict__ Qb,   // [BH][S][32]
    const _Float16* __restrict__ KRT,  // [B][S][256]
    const unsigned int* __restrict__ mbits, // [B][S][S/32]
    const float* __restrict__ esum_p,  // [4][BH][S]
    const float* __restrict__ accp,    // [4][BH][S][32]
    const float* __restrict__ Wfc, const float* __restrict__ bfc,
    const float* __restrict__ query, const float* __restrict__ gamma,
    const float* __restrict__ beta,
    float* __restrict__ attn_out,      // [BH][S][S]
    float* __restrict__ out_ln)        // [B*S][256]
{
    __shared__ __align__(16) char smem[33792];
    const int z = blockIdx.z;
    const int t = threadIdx.x;
    const long BHS = (long)BH * Sc;
    if (z < 16) {
        // ---- attn store tile ----
        constexpr int LDA = 132;
        float (*a_lds)[16][LDA] = (float(*)[16][LDA])smem;
        const int nt = blockIdx.x;
        const int q0 = blockIdx.y * 64;
        const int bh = z;
        const int b = bh >> 3, h = bh & 7;
        const int lane = t & 63, w = t >> 6;
        const int c = lane & 15, g = lane >> 4;
        const int q = q0 + w * 16 + c;
        const int n0 = nt * 128;
        const f16x8 qf = *(const f16x8*)&Qb[((long)bh * Sc + q) * DKc + g * 8];
        const _Float16* krt = KRT + (long)b * Sc * 256 + h * 32;
        const long row = (long)bh * Sc + q;
        const float es = esum_p[row] + esum_p[BHS + row]
                       + esum_p[2 * BHS + row] + esum_p[3 * BHS + row];
        const float rinv = 1.f / es;
        const f32x4 zero = {};

        f32x4 s[8];
        #pragma unroll
        for (int nf = 0; nf < 8; ++nf) {
            f16x8 kf = *(const f16x8*)&krt[(long)(n0 + nf * 16 + c) * 256 + g * 8];
            s[nf] = __builtin_amdgcn_mfma_f32_16x16x32_f16(kf, qf, zero, 0, 0, 0);
        }
        const uint4 mq = *(const uint4*)&mbits[((long)b * Sc + q) * (Sc / 32) + nt * 4];
        const unsigned int mwv[4] = {mq.x, mq.y, mq.z, mq.w};
        #pragma unroll
        for (int nf = 0; nf < 8; ++nf) {
            const unsigned int bits = mwv[nf >> 1] >> ((nf & 1) * 16 + g * 4);
            f32x4 av;
            #pragma unroll
            for (int i = 0; i < 4; ++i)
                av[i] = ((bits >> i) & 1u) ? 0.f : __expf(s[nf][i]) * rinv;
            *(f32x4*)&a_lds[w][c][nf * 16 + g * 4] = av;
        }
        float* aoutw = attn_out + (long)bh * Sc * Sc
                     + (long)(q0 + w * 16 + (lane >> 5)) * Sc + (lane & 31) * 4 + n0;
        #pragma unroll
        for (int r2 = 0; r2 < 8; ++r2) {
            f32x4 v = *(const f32x4*)&a_lds[w][r2 * 2 + (lane >> 5)][(lane & 31) * 4];
            __builtin_nontemporal_store(v, (f32x4*)&aoutw[(long)(r2 * 2) * Sc]);
        }
    } else {
        // ---- LayerNorm output (8 rows per block) ----
        float (*xs)[Dc] = (float(*)[Dc])smem;
        float (*ys)[Dc] = (float(*)[Dc])(smem + 8 * Dc * 4);
        const int flat = blockIdx.x * 32 + blockIdx.y;   // 0..511
        const int r0 = flat * 8;
        const int h = t >> 5, dk = t & 31;
        #pragma unroll
        for (int i = 0; i < 8; ++i) {
            const long row = r0 + i;                 // b*S + q
            const int b = (int)(row >> 11);
            const int q = (int)(row & 2047);
            const long bhq = ((long)(b * Hc + h)) * Sc + q;
            float es = 0.f, av = 0.f;
            #pragma unroll
            for (int ns = 0; ns < 4; ++ns) {
                es += esum_p[ns * BHS + bhq];
                av += accp[(ns * BHS + bhq) * 32 + dk];
            }
            xs[i][t] = av / es;
        }
        __syncthreads();
        float acc[8];
        #pragma unroll
        for (int i = 0; i < 8; ++i) acc[i] = 0.f;
        for (int d = 0; d < Dc; ++d) {
            float wv = Wfc[d * Dc + t];
            #pragma unroll
            for (int i = 0; i < 8; ++i) acc[i] = fmaf(xs[i][d], wv, acc[i]);
        }
        const float bias = bfc[t];
        #pragma unroll
        for (int i = 0; i < 8; ++i)
            ys[i][t] = acc[i] + bias + query[(long)(r0 + i) * Dc + t];
        __syncthreads();
        const int w = t >> 6, lane = t & 63;
        #pragma unroll
        for (int rr2 = 0; rr2 < 2; ++rr2) {
            const int ri = w * 2 + rr2;
            float x0 = ys[ri][lane], x1 = ys[ri][lane + 64];
            float x2 = ys[ri][lane + 128], x3 = ys[ri][lane + 192];
            float sum = x0 + x1 + x2 + x3;
            float sq = x0 * x0 + x1 * x1 + x2 * x2 + x3 * x3;
            for (int off = 32; off; off >>= 1) {
                sum += __shfl_down(sum, off);
                sq  += __shfl_down(sq, off);
            }
            sum = __shfl(sum, 0);
            sq  = __shfl(sq, 0);
            const float mu = sum * (1.f / 256.f);
            const float var = sq * (1.f / 256.f) - mu * mu;
            const float rstd = rsqrtf(var + 1e-5f);
            float* orow = out_ln + (long)(r0 + ri) * Dc;
            orow[lane]       = (x0 - mu) * rstd * gamma[lane]       + beta[lane];
            orow[lane + 64]  = (x1 - mu) * rstd * gamma[lane + 64]  + beta[lane + 64];
            orow[lane + 128] = (x2 - mu) * rstd * gamma[lane + 128] + beta[lane + 128];
            orow[lane + 192] = (x3 - mu) * rstd * gamma[lane + 192] + beta[lane + 192];
        }
    }
}

// ---------------------------------------------------------------------------
extern "C" void kernel_launch(void* const* d_in, const int* in_sizes, int n_in,
                              void* d_out, int out_size, void* d_ws, size_t ws_size,
                              hipStream_t stream)
{
    const float* query   = (const float*)d_in[0];
    const float* key_    = (const float*)d_in[1];
    const float* value   = (const float*)d_in[2];
    const unsigned int* mask = (const unsigned int*)d_in[3];
    const float* relation = (const float*)d_in[4];
    const float* Wq  = (const float*)d_in[5];
    const float* Wk  = (const float*)d_in[6];
    const float* Wv  = (const float*)d_in[7];
    const float* Wfc = (const float*)d_in[8];
    const float* bfc = (const float*)d_in[9];
    const float* gamma = (const float*)d_in[10];
    const float* beta  = (const float*)d_in[11];

    float* out_ln   = (float*)d_out;
    float* out_attn = (float*)d_out + (size_t)Bc * Sc * Dc;

    char* ws = (char*)d_ws;
    _Float16* Qb   = (_Float16*)(ws + 0);          //  2 MB [BH][S][32]
    _Float16* Kt   = (_Float16*)(ws + 2097152);    //  2 MB [B][H][32][S]
    _Float16* Vt   = (_Float16*)(ws + 4194304);    //  2 MB [BH][32][S]
    _Float16* KRT  = (_Float16*)(ws + 6291456);    //  2 MB [B][S][256]
    unsigned int* mbits = (unsigned int*)(ws + 8388608);  // 1 MB
    float*    KRp   = (float*)  (ws + 9437184);    // 16.8 MB [4][B][S][256]
    float*    esum_p= (float*)  (ws + 26214400);   // 512 KB [4][BH][S]
    float*    accp  = (float*)  (ws + 26738688);   // 16.8 MB [4][BH][S][32]

    prep_kernel<<<dim3(2560), 256, 0, stream>>>(
        query, key_, value, Wq, Wk, Wv, mask, Qb, Kt, Vt, mbits);
    kr_kernel<<<dim3(4, Sc / 64, Bc * 4), 256, 0, stream>>>(relation, Kt, KRp);
    krc_kernel<<<dim3(1024), 256, 0, stream>>>(KRp, KRT);
    attn_pv_kernel<<<dim3(Sc / 64, BH, 4), 256, 0, stream>>>(
        Qb, KRT, Vt, mbits, esum_p, accp);
    finish_kernel<<<dim3(Sc / 128, Sc / 64, 17), 256, 0, stream>>>(
        Qb, KRT, mbits, esum_p, accp, Wfc, bfc, query, gamma, beta,
        out_attn, out_ln);
}

// Round 11
// 201.415 us; speedup vs baseline: 1.0629x; 1.0629x over previous
//
#include <hip/hip_runtime.h>

// Problem constants
constexpr int Bc = 2, Sc = 2048, Dc = 256, Hc = 8, DKc = 32;
constexpr int BH = Bc * Hc;

typedef _Float16 f16x8 __attribute__((ext_vector_type(8)));
typedef _Float16 f16x4 __attribute__((ext_vector_type(4)));
typedef float    f32x4 __attribute__((ext_vector_type(4)));

// ---------------------------------------------------------------------------
// K1: fused prep.  blocks [0,1536): proj (z=bx/512: 0=Q,1=K^T,2=V^T)
//                  blocks [1536,3584): relT 64x64 transpose tiles
//                  blocks [3584,4608): maskpack (1024 blocks — full coverage)
// ---------------------------------------------------------------------------
__global__ __launch_bounds__(256) void prep_kernel(
    const float* __restrict__ query, const float* __restrict__ key_,
    const float* __restrict__ value, const float* __restrict__ Wq,
    const float* __restrict__ Wk, const float* __restrict__ Wv,
    const float* __restrict__ rel, const unsigned int* __restrict__ mask,
    _Float16* __restrict__ Qb, _Float16* __restrict__ Kt,
    _Float16* __restrict__ Vt, _Float16* __restrict__ relT,
    unsigned int* __restrict__ mbits)
{
    __shared__ __align__(16) char smem[16640];
    const int bx = blockIdx.x;
    const int t = threadIdx.x;
    if (bx < 1536) {
        // ---- projection ----
        constexpr int ROWS = 8;
        float (*xs)[Dc] = (float(*)[Dc])smem;
        const int z = bx >> 9;
        const int lb = bx & 511;
        const float* X = (z == 0) ? query : (z == 1) ? key_ : value;
        const float* W = (z == 0) ? Wq : (z == 1) ? Wk : Wv;
        _Float16* out = (z == 0) ? Qb : (z == 1) ? Kt : Vt;
        const int vtrans = (z != 0);
        const float scale = (z == 0) ? 0.17677669529663689f : 1.0f;
        const int r0 = lb * ROWS;
        #pragma unroll
        for (int i = 0; i < ROWS; ++i)
            xs[i][t] = X[(long)(r0 + i) * Dc + t];
        __syncthreads();
        float acc[ROWS];
        #pragma unroll
        for (int i = 0; i < ROWS; ++i) acc[i] = 0.f;
        for (int d = 0; d < Dc; ++d) {
            float w = W[d * Dc + t];
            #pragma unroll
            for (int i = 0; i < ROWS; ++i) acc[i] = fmaf(xs[i][d], w, acc[i]);
        }
        const int h = t >> 5, dk = t & 31;
        #pragma unroll
        for (int i = 0; i < ROWS; ++i) {
            int row = r0 + i;
            int b = row >> 11, s = row & 2047;
            long idx = vtrans ? (((long)(b * Hc + h) * DKc + dk) * Sc + s)
                              : (((long)(b * Hc + h) * Sc + s) * DKc + dk);
            out[idx] = (_Float16)(acc[i] * scale);
        }
    } else if (bx < 3584) {
        // ---- relT: relT[b][n][k] = rel[b][k][n] ----
        float (*tile)[65] = (float(*)[65])smem;
        const int idx = bx - 1536;
        const int b = idx >> 10;
        const int rem = idx & 1023;
        const int k0 = (rem >> 5) * 64, n0 = (rem & 31) * 64;
        const int r = t >> 4;
        const int c4 = (t & 15) * 4;
        const float* src = rel + (long)b * Sc * Sc;
        #pragma unroll
        for (int i = 0; i < 4; ++i) {
            f32x4 v = *(const f32x4*)&src[(long)(k0 + i * 16 + r) * Sc + n0 + c4];
            *(f32x4*)&tile[i * 16 + r][c4] = v;
        }
        __syncthreads();
        _Float16* dst = relT + (long)b * Sc * Sc;
        #pragma unroll
        for (int i = 0; i < 4; ++i) {
            const int n = i * 16 + r;
            f16x4 o;
            #pragma unroll
            for (int e = 0; e < 4; ++e) o[e] = (_Float16)tile[c4 + e][n];
            *(f16x4*)&dst[(long)(n0 + n) * Sc + k0 + c4] = o;
        }
    } else {
        // ---- maskpack: 1024 blocks cover all 262144 output uints ----
        const int idx = (bx - 3584) * 256 + t;
        const uint4 a = ((const uint4*)mask)[idx * 2];
        const uint4 b = ((const uint4*)mask)[idx * 2 + 1];
        unsigned int wsv[8] = {a.x, a.y, a.z, a.w, b.x, b.y, b.z, b.w};
        unsigned int r = 0;
        #pragma unroll
        for (int j = 0; j < 8; ++j) {
            unsigned int nib = (wsv[j] | (wsv[j] >> 7) | (wsv[j] >> 14) | (wsv[j] >> 21)) & 0xFu;
            r |= nib << (4 * j);
        }
        mbits[idx] = r;
    }
}

// ---------------------------------------------------------------------------
// K2: KR GEMM, k-split x2.  KRp[ks][b][n][hd] = sum_{k half} relT * Kt
// BM=BN=64, BK=64, 4 waves (2x2); grid (4 hd, 32 n, b*2+ks) = 512 blocks.
// ---------------------------------------------------------------------------
__global__ __launch_bounds__(256) void kr_kernel(
    const _Float16* __restrict__ relT, const _Float16* __restrict__ Kt,
    float* __restrict__ KRp)
{
    constexpr int LDK = 72;
    __shared__ _Float16 As[64][LDK];
    __shared__ _Float16 Bs[64][LDK];
    const int z = blockIdx.z;
    const int b = z >> 1, ks = z & 1;
    const int m0 = blockIdx.y * 64;
    const int n0 = blockIdx.x * 64;
    const _Float16* Ap = relT + (long)b * Sc * Sc;
    const _Float16* Bp = Kt + (long)b * Hc * DKc * Sc;
    const int t = threadIdx.x;
    const int lane = t & 63, wave = t >> 6;
    const int wr = wave >> 1, wc = wave & 1;
    const int c = lane & 15, g = lane >> 4;
    const int lrow = t >> 2;
    const int lcol = (t & 3) * 16;
    f32x4 acc[2][2] = {};
    for (int k0 = ks * 1024; k0 < ks * 1024 + 1024; k0 += 64) {
        *(f16x8*)&As[lrow][lcol]     = *(const f16x8*)&Ap[(long)(m0 + lrow) * Sc + k0 + lcol];
        *(f16x8*)&As[lrow][lcol + 8] = *(const f16x8*)&Ap[(long)(m0 + lrow) * Sc + k0 + lcol + 8];
        *(f16x8*)&Bs[lrow][lcol]     = *(const f16x8*)&Bp[(long)(n0 + lrow) * Sc + k0 + lcol];
        *(f16x8*)&Bs[lrow][lcol + 8] = *(const f16x8*)&Bp[(long)(n0 + lrow) * Sc + k0 + lcol + 8];
        __syncthreads();
        #pragma unroll
        for (int kk = 0; kk < 2; ++kk) {
            const int kb = kk * 32 + g * 8;
            f16x8 af[2], bf[2];
            #pragma unroll
            for (int m = 0; m < 2; ++m)
                af[m] = *(const f16x8*)&As[wr * 32 + m * 16 + c][kb];
            #pragma unroll
            for (int n = 0; n < 2; ++n)
                bf[n] = *(const f16x8*)&Bs[wc * 32 + n * 16 + c][kb];
            #pragma unroll
            for (int m = 0; m < 2; ++m)
                #pragma unroll
                for (int n = 0; n < 2; ++n)
                    acc[m][n] = __builtin_amdgcn_mfma_f32_16x16x32_f16(
                        af[m], bf[n], acc[m][n], 0, 0, 0);
        }
        __syncthreads();
    }
    float* outp = KRp + ((long)ks * Bc + b) * Sc * 256;
    #pragma unroll
    for (int m = 0; m < 2; ++m)
        #pragma unroll
        for (int n = 0; n < 2; ++n)
            #pragma unroll
            for (int i = 0; i < 4; ++i) {
                int row = m0 + wr * 32 + m * 16 + g * 4 + i;
                int col = n0 + wc * 32 + n * 16 + c;
                outp[(long)row * 256 + col] = acc[m][n][i];
            }
}

// ---------------------------------------------------------------------------
// K2b: KRT = f16(KRp[0] + KRp[1])
// ---------------------------------------------------------------------------
__global__ __launch_bounds__(256) void krc_kernel(
    const float* __restrict__ KRp, _Float16* __restrict__ KRT)
{
    const long idx = ((long)blockIdx.x * 256 + threadIdx.x) * 4;
    const long half = (long)Bc * Sc * 256;
    f32x4 a = *(const f32x4*)&KRp[idx];
    f32x4 b = *(const f32x4*)&KRp[half + idx];
    f16x4 o;
    #pragma unroll
    for (int i = 0; i < 4; ++i) o[i] = (_Float16)(a[i] + b[i]);
    *(f16x4*)&KRT[idx] = o;
}

// ---------------------------------------------------------------------------
// K3a: esum + PV pass, n-split x4.  grid (32 q-tiles, BH, 4 ns) = 2048.
// Writes partial esum_p[ns][bh][q], UNNORMALIZED accp[ns][bh][q][32].
// ---------------------------------------------------------------------------
__global__ __launch_bounds__(256) void attn_pv_kernel(
    const _Float16* __restrict__ Qb,   // [BH][S][32], pre-scaled
    const _Float16* __restrict__ KRT,  // [B][S][256]
    const _Float16* __restrict__ Vt,   // [BH][32][S]
    const unsigned int* __restrict__ mbits, // [B][S][S/32]
    float* __restrict__ esum_p,        // [4][BH][S]
    float* __restrict__ accp)          // [4][BH][S][32]
{
    constexpr int NT = 128, LDP = 136;
    __shared__ _Float16 p_lds[64][LDP];
    const int bh = blockIdx.y;
    const int ns = blockIdx.z;
    const int b = bh >> 3, h = bh & 7;
    const int q0 = blockIdx.x * 64;
    const int t = threadIdx.x, lane = t & 63, w = t >> 6;
    const int c = lane & 15, g = lane >> 4;
    const int q = q0 + w * 16 + c;
    const f16x8 qf = *(const f16x8*)&Qb[((long)bh * Sc + q) * DKc + g * 8];
    const _Float16* krt = KRT + (long)b * Sc * 256 + h * 32;
    const unsigned int* mbitrow = mbits + ((long)b * Sc + q) * (Sc / 32);
    const f32x4 zero = {};
    f32x4 acc[2] = {};
    float esum = 0.f;

    for (int nt = ns * 4; nt < ns * 4 + 4; ++nt) {
        const int n0 = nt * NT;
        f32x4 s[8];
        #pragma unroll
        for (int nf = 0; nf < 8; ++nf) {
            f16x8 kf = *(const f16x8*)&krt[(long)(n0 + nf * 16 + c) * 256 + g * 8];
            s[nf] = __builtin_amdgcn_mfma_f32_16x16x32_f16(kf, qf, zero, 0, 0, 0);
        }
        const uint4 mq = *(const uint4*)&mbitrow[nt * 4];
        const unsigned int mwv[4] = {mq.x, mq.y, mq.z, mq.w};
        #pragma unroll
        for (int nf = 0; nf < 8; ++nf) {
            const unsigned int bits = mwv[nf >> 1] >> ((nf & 1) * 16 + g * 4);
            f16x4 pv;
            #pragma unroll
            for (int i = 0; i < 4; ++i) {
                float p = ((bits >> i) & 1u) ? 0.f : __expf(s[nf][i]);
                esum += p;
                pv[i] = (_Float16)p;
            }
            *(f16x4*)&p_lds[w * 16 + c][nf * 16 + g * 4] = pv;
        }
        #pragma unroll
        for (int ks = 0; ks < 4; ++ks) {
            f16x8 af = *(const f16x8*)&p_lds[w * 16 + c][ks * 32 + g * 8];
            #pragma unroll
            for (int nb = 0; nb < 2; ++nb) {
                f16x8 vf = *(const f16x8*)&Vt[((long)bh * DKc + nb * 16 + c) * Sc + n0 + ks * 32 + g * 8];
                acc[nb] = __builtin_amdgcn_mfma_f32_16x16x32_f16(af, vf, acc[nb], 0, 0, 0);
            }
        }
    }
    esum += __shfl_xor(esum, 16);
    esum += __shfl_xor(esum, 32);
    if (lane < 16)
        esum_p[((long)ns * BH + bh) * Sc + q0 + w * 16 + lane] = esum;
    #pragma unroll
    for (int nb = 0; nb < 2; ++nb)
        #pragma unroll
        for (int i = 0; i < 4; ++i) {
            const long qrow = q0 + w * 16 + g * 4 + i;
            accp[(((long)ns * BH + bh) * Sc + qrow) * 32 + nb * 16 + c] = acc[nb][i];
        }
}

// ---------------------------------------------------------------------------
// K4: finish.  z<16: attn store tile (nt=x, q-tile=y, bh=z).
//              z==16: LayerNorm output blocks (flat = x*32+y, 8 rows each).
// ---------------------------------------------------------------------------
__global__ __launch_bounds__(256) void finish_kernel(
    const _Float16* __restrict__ Qb,   // [BH][S][32]
    const _Float16* __restrict__ KRT,  // [B][S][256]
    const unsigned int* __restrict__ mbits, // [B][S][S/32]
    const float* __restrict__ esum_p,  // [4][BH][S]
    const float* __restrict__ accp,    // [4][BH][S][32]
    const float* __restrict__ Wfc, const float* __restrict__ bfc,
    const float* __restrict__ query, const float* __restrict__ gamma,
    const float* __restrict__ beta,
    float* __restrict__ attn_out,      // [BH][S][S]
    float* __restrict__ out_ln)        // [B*S][256]
{
    __shared__ __align__(16) char smem[33792];
    const int z = blockIdx.z;
    const int t = threadIdx.x;
    const long BHS = (long)BH * Sc;
    if (z < 16) {
        // ---- attn store tile ----
        constexpr int LDA = 132;
        float (*a_lds)[16][LDA] = (float(*)[16][LDA])smem;
        const int nt = blockIdx.x;
        const int q0 = blockIdx.y * 64;
        const int bh = z;
        const int b = bh >> 3, h = bh & 7;
        const int lane = t & 63, w = t >> 6;
        const int c = lane & 15, g = lane >> 4;
        const int q = q0 + w * 16 + c;
        const int n0 = nt * 128;
        const f16x8 qf = *(const f16x8*)&Qb[((long)bh * Sc + q) * DKc + g * 8];
        const _Float16* krt = KRT + (long)b * Sc * 256 + h * 32;
        const long row = (long)bh * Sc + q;
        const float es = esum_p[row] + esum_p[BHS + row]
                       + esum_p[2 * BHS + row] + esum_p[3 * BHS + row];
        const float rinv = 1.f / es;
        const f32x4 zero = {};

        f32x4 s[8];
        #pragma unroll
        for (int nf = 0; nf < 8; ++nf) {
            f16x8 kf = *(const f16x8*)&krt[(long)(n0 + nf * 16 + c) * 256 + g * 8];
            s[nf] = __builtin_amdgcn_mfma_f32_16x16x32_f16(kf, qf, zero, 0, 0, 0);
        }
        const uint4 mq = *(const uint4*)&mbits[((long)b * Sc + q) * (Sc / 32) + nt * 4];
        const unsigned int mwv[4] = {mq.x, mq.y, mq.z, mq.w};
        #pragma unroll
        for (int nf = 0; nf < 8; ++nf) {
            const unsigned int bits = mwv[nf >> 1] >> ((nf & 1) * 16 + g * 4);
            f32x4 av;
            #pragma unroll
            for (int i = 0; i < 4; ++i)
                av[i] = ((bits >> i) & 1u) ? 0.f : __expf(s[nf][i]) * rinv;
            *(f32x4*)&a_lds[w][c][nf * 16 + g * 4] = av;
        }
        float* aoutw = attn_out + (long)bh * Sc * Sc
                     + (long)(q0 + w * 16 + (lane >> 5)) * Sc + (lane & 31) * 4 + n0;
        #pragma unroll
        for (int r2 = 0; r2 < 8; ++r2) {
            f32x4 v = *(const f32x4*)&a_lds[w][r2 * 2 + (lane >> 5)][(lane & 31) * 4];
            __builtin_nontemporal_store(v, (f32x4*)&aoutw[(long)(r2 * 2) * Sc]);
        }
    } else {
        // ---- LayerNorm output (8 rows per block) ----
        float (*xs)[Dc] = (float(*)[Dc])smem;
        float (*ys)[Dc] = (float(*)[Dc])(smem + 8 * Dc * 4);
        const int flat = blockIdx.x * 32 + blockIdx.y;   // 0..511
        const int r0 = flat * 8;
        const int h = t >> 5, dk = t & 31;
        #pragma unroll
        for (int i = 0; i < 8; ++i) {
            const long row = r0 + i;                 // b*S + q
            const int b = (int)(row >> 11);
            const int q = (int)(row & 2047);
            const long bhq = ((long)(b * Hc + h)) * Sc + q;
            float es = 0.f, av = 0.f;
            #pragma unroll
            for (int ns = 0; ns < 4; ++ns) {
                es += esum_p[ns * BHS + bhq];
                av += accp[(ns * BHS + bhq) * 32 + dk];
            }
            xs[i][t] = av / es;
        }
        __syncthreads();
        float acc[8];
        #pragma unroll
        for (int i = 0; i < 8; ++i) acc[i] = 0.f;
        for (int d = 0; d < Dc; ++d) {
            float wv = Wfc[d * Dc + t];
            #pragma unroll
            for (int i = 0; i < 8; ++i) acc[i] = fmaf(xs[i][d], wv, acc[i]);
        }
        const float bias = bfc[t];
        #pragma unroll
        for (int i = 0; i < 8; ++i)
            ys[i][t] = acc[i] + bias + query[(long)(r0 + i) * Dc + t];
        __syncthreads();
        const int w = t >> 6, lane = t & 63;
        #pragma unroll
        for (int rr2 = 0; rr2 < 2; ++rr2) {
            const int ri = w * 2 + rr2;
            float x0 = ys[ri][lane], x1 = ys[ri][lane + 64];
            float x2 = ys[ri][lane + 128], x3 = ys[ri][lane + 192];
            float sum = x0 + x1 + x2 + x3;
            float sq = x0 * x0 + x1 * x1 + x2 * x2 + x3 * x3;
            for (int off = 32; off; off >>= 1) {
                sum += __shfl_down(sum, off);
                sq  += __shfl_down(sq, off);
            }
            sum = __shfl(sum, 0);
            sq  = __shfl(sq, 0);
            const float mu = sum * (1.f / 256.f);
            const float var = sq * (1.f / 256.f) - mu * mu;
            const float rstd = rsqrtf(var + 1e-5f);
            float* orow = out_ln + (long)(r0 + ri) * Dc;
            orow[lane]       = (x0 - mu) * rstd * gamma[lane]       + beta[lane];
            orow[lane + 64]  = (x1 - mu) * rstd * gamma[lane + 64]  + beta[lane + 64];
            orow[lane + 128] = (x2 - mu) * rstd * gamma[lane + 128] + beta[lane + 128];
            orow[lane + 192] = (x3 - mu) * rstd * gamma[lane + 192] + beta[lane + 192];
        }
    }
}

// ---------------------------------------------------------------------------
extern "C" void kernel_launch(void* const* d_in, const int* in_sizes, int n_in,
                              void* d_out, int out_size, void* d_ws, size_t ws_size,
                              hipStream_t stream)
{
    const float* query   = (const float*)d_in[0];
    const float* key_    = (const float*)d_in[1];
    const float* value   = (const float*)d_in[2];
    const unsigned int* mask = (const unsigned int*)d_in[3];
    const float* relation = (const float*)d_in[4];
    const float* Wq  = (const float*)d_in[5];
    const float* Wk  = (const float*)d_in[6];
    const float* Wv  = (const float*)d_in[7];
    const float* Wfc = (const float*)d_in[8];
    const float* bfc = (const float*)d_in[9];
    const float* gamma = (const float*)d_in[10];
    const float* beta  = (const float*)d_in[11];

    float* out_ln   = (float*)d_out;
    float* out_attn = (float*)d_out + (size_t)Bc * Sc * Dc;

    char* ws = (char*)d_ws;
    _Float16* Qb   = (_Float16*)(ws + 0);          //  2 MB [BH][S][32]
    _Float16* Kt   = (_Float16*)(ws + 2097152);    //  2 MB [B][H][32][S]
    _Float16* Vt   = (_Float16*)(ws + 4194304);    //  2 MB [BH][32][S]
    _Float16* relT = (_Float16*)(ws + 6291456);    // 16.8 MB [B][S][S] (n,k)
    _Float16* KRT  = (_Float16*)(ws + 23068672);   //  2 MB [B][S][256]
    unsigned int* mbits = (unsigned int*)(ws + 25165824); // 1 MB
    float*    KRp   = (float*)  (ws + 26214400);   // 8.4 MB [2][B][S][256]
    float*    esum_p= (float*)  (ws + 34603008);   // 512 KB [4][BH][S]
    float*    accp  = (float*)  (ws + 35127296);   // 16.8 MB [4][BH][S][32]

    prep_kernel<<<dim3(4608), 256, 0, stream>>>(
        query, key_, value, Wq, Wk, Wv, relation, mask,
        Qb, Kt, Vt, relT, mbits);
    kr_kernel<<<dim3(4, Sc / 64, Bc * 2), 256, 0, stream>>>(relT, Kt, KRp);
    krc_kernel<<<dim3(Bc * Sc * 256 / 4 / 256), 256, 0, stream>>>(KRp, KRT);
    attn_pv_kernel<<<dim3(Sc / 64, BH, 4), 256, 0, stream>>>(
        Qb, KRT, Vt, mbits, esum_p, accp);
    finish_kernel<<<dim3(Sc / 128, Sc / 64, 17), 256, 0, stream>>>(
        Qb, KRT, mbits, esum_p, accp, Wfc, bfc, query, gamma, beta,
        out_attn, out_ln);
}